// Round 12
// baseline (858.991 us; speedup 1.0000x reference)
//
#include <hip/hip_runtime.h>
#include <math.h>

#define NN 50000
#define EE 800000
#define ET (EE + NN)            // CSR slots incl. self-loops
#define FIN 128
#define HH 8
#define CC 64
#define HC 512
#define HU 256                  // h row in uints (2 bf16 per uint)
#define GG 64
#define POOL_SZ (GG * 3 * CC)   // 12288

typedef short short8 __attribute__((ext_vector_type(8)));
typedef float floatx4 __attribute__((ext_vector_type(4)));

__device__ __forceinline__ unsigned bf16pack(float a, float b) {
    unsigned ua = __float_as_uint(a), ub = __float_as_uint(b);
    ua = (ua + 0x7FFFu + ((ua >> 16) & 1u)) >> 16;          // RNE
    ub = (ub + 0x7FFFu + ((ub >> 16) & 1u)) >> 16;
    return ua | (ub << 16);
}
__device__ __forceinline__ unsigned short bf16r(float a) {
    unsigned ua = __float_as_uint(a);
    return (unsigned short)((ua + 0x7FFFu + ((ua >> 16) & 1u)) >> 16);
}
__device__ __forceinline__ float bf_lo(unsigned u) { return __uint_as_float(u << 16); }
__device__ __forceinline__ float bf_hi(unsigned u) { return __uint_as_float(u & 0xFFFF0000u); }

// ---------------- f32 -> bf16 bulk convert (x once per launch) ----------------

__global__ void k_cvt(const float* __restrict__ in, unsigned* __restrict__ out, int n8) {
    int i = blockIdx.x * blockDim.x + threadIdx.x;
    if (i < n8) {
        float4 a = ((const float4*)in)[i * 2];
        float4 b = ((const float4*)in)[i * 2 + 1];
        uint4 o;
        o.x = bf16pack(a.x, a.y); o.y = bf16pack(a.z, a.w);
        o.z = bf16pack(b.x, b.y); o.w = bf16pack(b.z, b.w);
        ((uint4*)out)[i] = o;
    }
}

// ---------------- W f32 [K][512] -> MFMA-ready bf16 Wq[kg][col][e] ----------------

__global__ void k_wprep(const float* __restrict__ W, unsigned short* __restrict__ Wq, int KG) {
    int g = blockIdx.x * blockDim.x + threadIdx.x;   // kg*512 + col
    if (g >= KG * 512) return;
    int kg = g >> 9, col = g & 511;
    #pragma unroll
    for (int e = 0; e < 8; ++e)
        Wq[(size_t)g * 8 + e] = bf16r(W[(size_t)(kg * 8 + e) * HC + col]);
}

// ---------------- CSR build ----------------

__global__ void k_init(int* cnt) {
    int i = blockIdx.x * blockDim.x + threadIdx.x;
    if (i < NN) cnt[i] = 1;                 // reserve self-loop slot
}

__global__ void k_count(const int* __restrict__ dst, int* cnt) {
    int e = blockIdx.x * blockDim.x + threadIdx.x;
    if (e < EE) atomicAdd(&cnt[dst[e]], 1);
}

#define SCAN_B 256
__global__ void k_scan1(const int* __restrict__ cnt, int* off, int* bsum, int n) {
    __shared__ int s[SCAN_B];
    int i = blockIdx.x * SCAN_B + threadIdx.x;
    int v = (i < n) ? cnt[i] : 0;
    s[threadIdx.x] = v;
    __syncthreads();
    for (int d = 1; d < SCAN_B; d <<= 1) {
        int t = (threadIdx.x >= d) ? s[threadIdx.x - d] : 0;
        __syncthreads();
        s[threadIdx.x] += t;
        __syncthreads();
    }
    if (i < n) off[i] = s[threadIdx.x] - v;
    if (threadIdx.x == SCAN_B - 1) bsum[blockIdx.x] = s[SCAN_B - 1];
}

__global__ void k_scan2(int* bsum, int nb) {
    __shared__ int s[SCAN_B];
    int v = (threadIdx.x < nb) ? bsum[threadIdx.x] : 0;
    s[threadIdx.x] = v;
    __syncthreads();
    for (int d = 1; d < SCAN_B; d <<= 1) {
        int t = (threadIdx.x >= d) ? s[threadIdx.x - d] : 0;
        __syncthreads();
        s[threadIdx.x] += t;
        __syncthreads();
    }
    if (threadIdx.x < nb) bsum[threadIdx.x] = s[threadIdx.x] - v;
}

__global__ void k_scan3(int* off, const int* __restrict__ bsum, int* cursor, int n, int total) {
    int i = blockIdx.x * blockDim.x + threadIdx.x;
    if (i < n) {
        int v = off[i] + bsum[i / SCAN_B];
        off[i] = v;
        cursor[i] = v + 1;                  // slot off[i] = self loop
    }
    if (i == 0) off[n] = total;
}

__global__ void k_fillself(const int* __restrict__ off, int* col) {
    int i = blockIdx.x * blockDim.x + threadIdx.x;
    if (i < NN) col[off[i]] = i;
}

__global__ void k_fill(const int* __restrict__ src, const int* __restrict__ dst,
                       int* cursor, int* col) {
    int e = blockIdx.x * blockDim.x + threadIdx.x;
    if (e < EE) {
        int p = atomicAdd(&cursor[dst[e]], 1);
        col[p] = src[e];
    }
}

// ---------------- MFMA GEMM, no LDS / no barriers ----------------
// grid (M/64, 8 heads), 256 threads = 4 waves; wave w computes rows
// [64*bx + 16w, +16) x 64 cols (one head). A-frags and B-frags read directly
// from global (A is L3-resident; Wq is 256 KB, L2-hot). Epilogue fuses
// a_src/a_dst dot-products (f32 accum) + bf16 h-store.

template<int K>
__global__ __launch_bounds__(256) void k_gemm2(
        const unsigned short* __restrict__ A,    // bf16 [M][K]
        const unsigned short* __restrict__ Wq,   // bf16 [K/8][512][8]
        const float* __restrict__ asrc, const float* __restrict__ adst,
        unsigned short* __restrict__ hout,       // bf16 [M][512]
        float* __restrict__ as_out, float* __restrict__ ad_out, int M) {
    const int head = blockIdx.y;
    const int col0 = head * 64;
    const int w    = threadIdx.x >> 6;
    const int lane = threadIdx.x & 63;
    const int l15  = lane & 15;
    const int kgl  = lane >> 4;
    const int row  = blockIdx.x * 64 + w * 16 + l15;
    const bool okr = row < M;

    floatx4 acc[4] = {};
    const unsigned short* ap = A + (size_t)row * K + kgl * 8;
    #pragma unroll
    for (int kt = 0; kt < K / 32; ++kt) {
        short8 af = {};
        if (okr) af = *(const short8*)(ap + kt * 32);
        #pragma unroll
        for (int fj = 0; fj < 4; ++fj) {
            const unsigned short* bp =
                Wq + ((size_t)((kt * 4 + kgl) * 512) + col0 + fj * 16 + l15) * 8;
            short8 bf = *(const short8*)bp;
            acc[fj] = __builtin_amdgcn_mfma_f32_16x16x32_bf16(af, bf, acc[fj], 0, 0, 0);
        }
    }

    // epilogue: C/D mapping col=l15, row=4*(lane>>4)+reg within the 16-row stripe
    float sav[4], dav[4];
    #pragma unroll
    for (int fj = 0; fj < 4; ++fj) {
        sav[fj] = asrc[col0 + 16 * fj + l15];
        dav[fj] = adst[col0 + 16 * fj + l15];
    }
    const int r4 = lane >> 4;
    const int row0 = blockIdx.x * 64;
    #pragma unroll
    for (int reg = 0; reg < 4; ++reg) {
        int gr = row0 + 16 * w + r4 * 4 + reg;
        float ps = acc[0][reg] * sav[0] + acc[1][reg] * sav[1]
                 + acc[2][reg] * sav[2] + acc[3][reg] * sav[3];
        float pd = acc[0][reg] * dav[0] + acc[1][reg] * dav[1]
                 + acc[2][reg] * dav[2] + acc[3][reg] * dav[3];
        ps += __shfl_xor(ps, 1); ps += __shfl_xor(ps, 2);
        ps += __shfl_xor(ps, 4); ps += __shfl_xor(ps, 8);
        pd += __shfl_xor(pd, 1); pd += __shfl_xor(pd, 2);
        pd += __shfl_xor(pd, 4); pd += __shfl_xor(pd, 8);
        if (gr < M) {
            #pragma unroll
            for (int fj = 0; fj < 4; ++fj)
                hout[(size_t)gr * HC + col0 + 16 * fj + l15] = bf16r(acc[fj][reg]);
            if (l15 == 0) {
                as_out[gr * HH + head] = ps;
                ad_out[gr * HH + head] = pd;
            }
        }
    }
}

// ---------------- wave-per-node softmax + gather (no max-shift) ----------------
// 256 threads = 4 waves = 4 nodes/block. No barriers, no atomics, no m-tracking:
// e is small by construction, so exp(e)/sum(exp(e)) is overflow-free and
// exact-math-identical to the max-shifted reference.

__global__ __launch_bounds__(256) void k_aggw(
        const unsigned* __restrict__ hb, const float* __restrict__ as,
        const float* __restrict__ ad, const int* __restrict__ off,
        const int* __restrict__ col, const float* __restrict__ bias,
        float* __restrict__ yout, unsigned* __restrict__ yb) {
    __shared__ float s_alpha[4][64][HH];
    __shared__ int   s_src[4][64];

    const int w    = threadIdx.x >> 6;
    const int lane = threadIdx.x & 63;
    const int n    = blockIdx.x * 4 + w;         // 12500*4 == NN exactly
    const int e0   = off[n];
    const int tot  = off[n + 1] - e0;            // >=1 (self loop in CSR)
    const int hsel = lane >> 5;                  // head parity of this lane

    float adv[HH];
    {
        float4 a0 = *(const float4*)&ad[n * HH];
        float4 a1 = *(const float4*)&ad[n * HH + 4];
        adv[0] = a0.x; adv[1] = a0.y; adv[2] = a0.z; adv[3] = a0.w;
        adv[4] = a1.x; adv[5] = a1.y; adv[6] = a1.z; adv[7] = a1.w;
    }

    float d4[4] = {0.f, 0.f, 0.f, 0.f};          // denom for heads {2i+hsel}
    float acc[8];
    #pragma unroll
    for (int i = 0; i < 8; ++i) acc[i] = 0.f;

    for (int base = 0; base < tot; base += 64) {
        const int cnt = min(64, tot - base);
        // ---- phase A: numerators for this chunk (lane j = edge base+j) ----
        float num[HH];
        if (lane < cnt) {
            int s = col[e0 + base + lane];
            s_src[w][lane] = s;
            float4 a0 = *(const float4*)&as[s * HH];
            float4 a1 = *(const float4*)&as[s * HH + 4];
            float e[HH];
            e[0] = a0.x + adv[0]; e[1] = a0.y + adv[1];
            e[2] = a0.z + adv[2]; e[3] = a0.w + adv[3];
            e[4] = a1.x + adv[4]; e[5] = a1.y + adv[5];
            e[6] = a1.z + adv[6]; e[7] = a1.w + adv[7];
            #pragma unroll
            for (int h = 0; h < HH; ++h) {
                e[h] = e[h] > 0.f ? e[h] : 0.2f * e[h];
                num[h] = __expf(e[h]);
            }
            *(float4*)&s_alpha[w][lane][0] = make_float4(num[0], num[1], num[2], num[3]);
            *(float4*)&s_alpha[w][lane][4] = make_float4(num[4], num[5], num[6], num[7]);
        } else {
            #pragma unroll
            for (int h = 0; h < HH; ++h) num[h] = 0.f;
        }
        // per-head denom partial via butterfly; keep only owned 4 heads
        #pragma unroll
        for (int h = 0; h < HH; ++h) {
            float v = num[h];
            v += __shfl_xor(v, 1);  v += __shfl_xor(v, 2);
            v += __shfl_xor(v, 4);  v += __shfl_xor(v, 8);
            v += __shfl_xor(v, 16); v += __shfl_xor(v, 32);
            num[h] = v;
        }
        #pragma unroll
        for (int i = 0; i < 4; ++i) d4[i] += num[2 * i + hsel];
        // ---- phase B: gather this chunk ----
        #define STEP(jj) { \
            int sj = s_src[w][jj]; \
            const unsigned* _p = &hb[(size_t)sj * HU + lane]; \
            unsigned u0 = _p[0], u1 = _p[64], u2 = _p[128], u3 = _p[192]; \
            float a0 = s_alpha[w][jj][hsel]; \
            float a1 = s_alpha[w][jj][2 + hsel]; \
            float a2 = s_alpha[w][jj][4 + hsel]; \
            float a3 = s_alpha[w][jj][6 + hsel]; \
            acc[0] += a0 * bf_lo(u0); acc[1] += a0 * bf_hi(u0); \
            acc[2] += a1 * bf_lo(u1); acc[3] += a1 * bf_hi(u1); \
            acc[4] += a2 * bf_lo(u2); acc[5] += a2 * bf_hi(u2); \
            acc[6] += a3 * bf_lo(u3); acc[7] += a3 * bf_hi(u3); }
        int j = 0;
        for (; j + 4 <= cnt; j += 4) { STEP(j); STEP(j + 1); STEP(j + 2); STEP(j + 3); }
        for (; j < cnt; ++j) STEP(j);
        #undef STEP
    }

    // normalize by denom
    #pragma unroll
    for (int i = 0; i < 4; ++i) {
        float r = 1.f / d4[i];
        acc[2 * i] *= r; acc[2 * i + 1] *= r;
    }
    // head mean: lane l and l^32 hold complementary head sets for channel pair l&31
    float sx = acc[0] + acc[2] + acc[4] + acc[6];
    float sy = acc[1] + acc[3] + acc[5] + acc[7];
    sx += __shfl_xor(sx, 32);
    sy += __shfl_xor(sy, 32);
    if (lane < 32) {
        float2 bv = *(const float2*)&bias[lane * 2];
        float vx = sx * 0.125f + bv.x;
        float vy = sy * 0.125f + bv.y;
        vx = vx > 0.f ? vx : (__expf(vx) - 1.f);
        vy = vy > 0.f ? vy : (__expf(vy) - 1.f);
        *(float2*)&yout[(size_t)n * CC + lane * 2] = make_float2(vx, vy);
        yb[(size_t)n * 32 + lane] = bf16pack(vx, vy);   // bf16 copy for next GEMM
    }
}

// ---------------- per-graph pooling (no atomics) ----------------

__global__ __launch_bounds__(256) void k_pool(
        const float* __restrict__ y, const int* __restrict__ batch,
        float* __restrict__ pooled, int layerOff) {
    __shared__ float red[256];
    const int g = blockIdx.x;
    const int t = threadIdx.x;
    int lo = 0, hi = NN;
    while (lo < hi) { int mid = (lo + hi) >> 1; if (batch[mid] < g) lo = mid + 1; else hi = mid; }
    const int nlo = lo;
    lo = nlo; hi = NN;
    while (lo < hi) { int mid = (lo + hi) >> 1; if (batch[mid] < g + 1) lo = mid + 1; else hi = mid; }
    const int nhi = lo;

    const int c = t & 63, r = t >> 6;
    float sum = 0.f;
    for (int n = nlo + r; n < nhi; n += 4) sum += y[(size_t)n * CC + c];
    red[t] = sum;
    __syncthreads();
    if (t < 64)
        pooled[g * (3 * CC) + layerOff + t] = red[t] + red[t + 64] + red[t + 128] + red[t + 192];
}

// ---------------- launch ----------------

extern "C" void kernel_launch(void* const* d_in, const int* in_sizes, int n_in,
                              void* d_out, int out_size, void* d_ws, size_t ws_size,
                              hipStream_t stream) {
    const float* x      = (const float*)d_in[0];
    const int*   ei     = (const int*)d_in[1];
    const int*   batch  = (const int*)d_in[2];
    const float* W0     = (const float*)d_in[4];
    const float* asrc0  = (const float*)d_in[5];
    const float* adst0  = (const float*)d_in[6];
    const float* b0     = (const float*)d_in[7];
    const float* W1     = (const float*)d_in[8];
    const float* asrc1  = (const float*)d_in[9];
    const float* adst1  = (const float*)d_in[10];
    const float* b1     = (const float*)d_in[11];
    const float* W2     = (const float*)d_in[12];
    const float* asrc2  = (const float*)d_in[13];
    const float* adst2  = (const float*)d_in[14];
    const float* b2     = (const float*)d_in[15];

    const int* src = ei;
    const int* dst = ei + EE;

    float* outp   = (float*)d_out;
    float* pooled = outp;                 // [64,192]
    float* hfinal = outp + POOL_SZ;       // [N,64]

    // workspace layout
    unsigned* hb     = (unsigned*)d_ws;                    // N*256 (bf16 x2)
    float*    y      = (float*)(hb + (size_t)NN * HU);     // N*64
    float*    as_buf = y + (size_t)NN * CC;                // N*8
    float*    ad_buf = as_buf + (size_t)NN * HH;           // N*8
    unsigned* xb     = (unsigned*)(ad_buf + (size_t)NN * HH); // N*64 (bf16 x2)
    unsigned* yb     = xb + (size_t)NN * 64;               // N*32 (bf16 x2)
    unsigned short* wq0 = (unsigned short*)(yb + (size_t)NN * 32); // 16*512*8
    unsigned short* wq1 = wq0 + (size_t)16 * 512 * 8;      // 8*512*8
    unsigned short* wq2 = wq1 + (size_t)8 * 512 * 8;       // 8*512*8
    int*      off    = (int*)(wq2 + (size_t)8 * 512 * 8);  // N+1
    int*      cursor = off + (NN + 1);                     // N
    int*      cnt    = cursor + NN;                        // N
    int*      col    = cnt + NN;                           // ET
    int*      bsum   = col + ET;                           // <=256

    const int NB = (NN + SCAN_B - 1) / SCAN_B;   // 196

    k_cvt<<<(NN * FIN / 8 + 255) / 256, 256, 0, stream>>>(x, xb, NN * FIN / 8);
    k_wprep<<<(16 * 512 + 255) / 256, 256, 0, stream>>>(W0, wq0, 16);
    k_wprep<<<(8 * 512 + 255) / 256, 256, 0, stream>>>(W1, wq1, 8);
    k_wprep<<<(8 * 512 + 255) / 256, 256, 0, stream>>>(W2, wq2, 8);
    k_init<<<(NN + 255) / 256, 256, 0, stream>>>(cnt);
    k_count<<<(EE + 255) / 256, 256, 0, stream>>>(dst, cnt);
    k_scan1<<<NB, SCAN_B, 0, stream>>>(cnt, off, bsum, NN);
    k_scan2<<<1, SCAN_B, 0, stream>>>(bsum, NB);
    k_scan3<<<(NN + 255) / 256, 256, 0, stream>>>(off, bsum, cursor, NN, ET);
    k_fillself<<<(NN + 255) / 256, 256, 0, stream>>>(off, col);
    k_fill<<<(EE + 255) / 256, 256, 0, stream>>>(src, dst, cursor, col);

    dim3 ggrid((NN + 63) / 64, HH);

    const unsigned short* wqs[3] = {wq0, wq1, wq2};
    const float* sa_[3]  = {asrc0, asrc1, asrc2};
    const float* da_[3]  = {adst0, adst1, adst2};
    const float* bb_[3]  = {b0, b1, b2};
    float* youts[3] = {y, y, hfinal};

    for (int L = 0; L < 3; ++L) {
        if (L == 0)
            k_gemm2<FIN><<<ggrid, 256, 0, stream>>>(
                (const unsigned short*)xb, wqs[0], sa_[0], da_[0],
                (unsigned short*)hb, as_buf, ad_buf, NN);
        else
            k_gemm2<CC><<<ggrid, 256, 0, stream>>>(
                (const unsigned short*)yb, wqs[L], sa_[L], da_[L],
                (unsigned short*)hb, as_buf, ad_buf, NN);
        k_aggw<<<NN / 4, 256, 0, stream>>>(hb, as_buf, ad_buf, off, col,
                                           bb_[L], youts[L], yb);
        k_pool<<<GG, 256, 0, stream>>>(youts[L], batch, pooled, L * CC);
    }
}